// Round 1
// baseline (483.891 us; speedup 1.0000x reference)
//
#include <hip/hip_runtime.h>
#include <hip/hip_bf16.h>
#include <math.h>

#define CHUNK 2048
#define EPSN 1e-12f

// ---------------------------------------------------------------------------
// Precompute face centers (SoA) from v,f.
// centers = normalize(mean of the 3 vertices)
// ---------------------------------------------------------------------------
__global__ __launch_bounds__(256)
void centers_kernel(const int* __restrict__ f,
                    const float* __restrict__ v,
                    float* __restrict__ cx,
                    float* __restrict__ cy,
                    float* __restrict__ cz,
                    int F)
{
    int i = blockIdx.x * 256 + threadIdx.x;
    if (i >= F) return;
    int a = f[i * 3 + 0], b = f[i * 3 + 1], c = f[i * 3 + 2];
    float mx = (v[a * 3 + 0] + v[b * 3 + 0] + v[c * 3 + 0]) * (1.0f / 3.0f);
    float my = (v[a * 3 + 1] + v[b * 3 + 1] + v[c * 3 + 1]) * (1.0f / 3.0f);
    float mz = (v[a * 3 + 2] + v[b * 3 + 2] + v[c * 3 + 2]) * (1.0f / 3.0f);
    float l = fmaxf(sqrtf(mx * mx + my * my + mz * mz), EPSN);
    float r = 1.0f / l;
    cx[i] = mx * r;
    cy[i] = my * r;
    cz[i] = mz * r;
}

// ---------------------------------------------------------------------------
// Init: rotation frame -> axis/angle -> Rodrigues rotate v.  Also packs v
// into float4 for aligned 16B gathers later.
// ---------------------------------------------------------------------------
__global__ __launch_bounds__(256)
void init_kernel(const float* __restrict__ x,
                 const float* __restrict__ v,
                 float4* __restrict__ v4,
                 float4* __restrict__ p0,
                 int N)
{
    int n = blockIdx.x * 256 + threadIdx.x;
    if (n >= N) return;

    float ax = x[n * 6 + 0], ay = x[n * 6 + 1], az = x[n * 6 + 2];
    float bx = x[n * 6 + 3], by = x[n * 6 + 4], bz = x[n * 6 + 5];

    // rot_x = norm(a)
    float l = fmaxf(sqrtf(ax * ax + ay * ay + az * az), EPSN);
    float rxx = ax / l, rxy = ay / l, rxz = az / l;
    // rot_z = norm(cross(rot_x, b))
    float czx = rxy * bz - rxz * by;
    float czy = rxz * bx - rxx * bz;
    float czz = rxx * by - rxy * bx;
    l = fmaxf(sqrtf(czx * czx + czy * czy + czz * czz), EPSN);
    float rzx = czx / l, rzy = czy / l, rzz = czz / l;
    // rot_y = norm(cross(rot_z, rot_x))
    float cyx = rzy * rxz - rzz * rxy;
    float cyy = rzz * rxx - rzx * rxz;
    float cyz = rzx * rxy - rzy * rxx;
    l = fmaxf(sqrtf(cyx * cyx + cyy * cyy + cyz * cyz), EPSN);
    float ryx = cyx / l, ryy = cyy / l, ryz = cyz / l;

    // axis-angle
    float axx = ryz - rzy;
    float axy = rzx - rxz;
    float axz = rxy - ryx;
    float trace = (rxx + ryy + rzz - 1.0f) * 0.5f;
    trace = fminf(fmaxf(trace, -1.0f + 1e-7f), 1.0f - 1e-7f);
    float angle = -acosf(trace) * (1.0f / 64.0f);   // / 2^K, K=6
    l = fmaxf(sqrtf(axx * axx + axy * axy + axz * axz), EPSN);
    axx /= l; axy /= l; axz /= l;

    float vx = v[n * 3 + 0], vy = v[n * 3 + 1], vz = v[n * 3 + 2];
    float d = axx * vx + axy * vy + axz * vz;
    float crx = axy * vz - axz * vy;
    float cry = axz * vx - axx * vz;
    float crz = axx * vy - axy * vx;
    float s, c;
    sincosf(angle, &s, &c);
    float omc = 1.0f - c;
    float px = vx * c + crx * s + axx * (d * omc);
    float py = vy * c + cry * s + axy * (d * omc);
    float pz = vz * c + crz * s + axz * (d * omc);

    p0[n] = make_float4(px, py, pz, 0.0f);
    v4[n] = make_float4(vx, vy, vz, 0.0f);
}

// ---------------------------------------------------------------------------
// One deformation iteration.  One wave (64 lanes) per point; 4 waves/block.
// Centers staged into LDS in 2048-center chunks shared by the whole block.
// ---------------------------------------------------------------------------
__global__ __launch_bounds__(256)
void iter_kernel(const float4* __restrict__ pin,
                 float4* __restrict__ pout,
                 const float* __restrict__ cx,
                 const float* __restrict__ cy,
                 const float* __restrict__ cz,
                 const int* __restrict__ f,
                 const float4* __restrict__ v4,
                 float* __restrict__ out_final,   // non-null on last iteration
                 int N, int F)
{
    __shared__ float scx[CHUNK];
    __shared__ float scy[CHUNK];
    __shared__ float scz[CHUNK];

    const int tid  = threadIdx.x;
    const int wave = tid >> 6;
    const int lane = tid & 63;
    const int pt   = blockIdx.x * 4 + wave;

    // normalized own point (all lanes load the same address -> broadcast)
    float pnx = 0.f, pny = 0.f, pnz = 0.f;
    if (pt < N) {
        float4 p = pin[pt];
        float l = fmaxf(sqrtf(p.x * p.x + p.y * p.y + p.z * p.z), EPSN);
        float r = 1.0f / l;
        pnx = p.x * r; pny = p.y * r; pnz = p.z * r;
    }

    float best = -1e30f;
    int bidx = 0;
    for (int base = 0; base < F; base += CHUNK) {
        for (int i = tid; i < CHUNK; i += 256) {
            scx[i] = cx[base + i];
            scy[i] = cy[base + i];
            scz[i] = cz[base + i];
        }
        __syncthreads();
        #pragma unroll 4
        for (int c = lane; c < CHUNK; c += 64) {
            float s = pnx * scx[c] + pny * scy[c] + pnz * scz[c];
            if (s > best) { best = s; bidx = base + c; }
        }
        __syncthreads();
    }

    // wave-wide argmax (first-occurrence tie-break to match np.argmax)
    for (int off = 32; off >= 1; off >>= 1) {
        float s2 = __shfl_xor(best, off);
        int   i2 = __shfl_xor(bidx, off);
        if (s2 > best || (s2 == best && i2 < bidx)) { best = s2; bidx = i2; }
    }

    if (pt < N && lane == 0) {
        int i0 = f[bidx * 3 + 0];
        int i1 = f[bidx * 3 + 1];
        int i2 = f[bidx * 3 + 2];
        float4 A = v4[i0];
        float4 B = v4[i1];
        float4 C = v4[i2];

        // Solve [A B C] b = pn via Cramer; det cancels in normalized bary.
        // D0 = pn . (B x C)
        float bcx = B.y * C.z - B.z * C.y;
        float bcy = B.z * C.x - B.x * C.z;
        float bcz = B.x * C.y - B.y * C.x;
        float D0 = pnx * bcx + pny * bcy + pnz * bcz;
        // D1 = A . (pn x C)
        float pcx = pny * C.z - pnz * C.y;
        float pcy = pnz * C.x - pnx * C.z;
        float pcz = pnx * C.y - pny * C.x;
        float D1 = A.x * pcx + A.y * pcy + A.z * pcz;
        // D2 = A . (B x pn)
        float bpx = B.y * pnz - B.z * pny;
        float bpy = B.z * pnx - B.x * pnz;
        float bpz = B.x * pny - B.y * pnx;
        float D2 = A.x * bpx + A.y * bpy + A.z * bpz;

        float inv = 1.0f / (D0 + D1 + D2);
        float w0 = D0 * inv, w1 = D1 * inv, w2 = D2 * inv;

        // gather + normalize neighbor p values (the field is normalized at
        // the start of each reference iteration)
        float4 q0 = pin[i0];
        float4 q1 = pin[i1];
        float4 q2 = pin[i2];
        float r0 = 1.0f / fmaxf(sqrtf(q0.x * q0.x + q0.y * q0.y + q0.z * q0.z), EPSN);
        float r1 = 1.0f / fmaxf(sqrtf(q1.x * q1.x + q1.y * q1.y + q1.z * q1.z), EPSN);
        float r2 = 1.0f / fmaxf(sqrtf(q2.x * q2.x + q2.y * q2.y + q2.z * q2.z), EPSN);

        float ox = w0 * q0.x * r0 + w1 * q1.x * r1 + w2 * q2.x * r2;
        float oy = w0 * q0.y * r0 + w1 * q1.y * r1 + w2 * q2.y * r2;
        float oz = w0 * q0.z * r0 + w1 * q1.z * r1 + w2 * q2.z * r2;

        if (out_final) {
            float l = fmaxf(sqrtf(ox * ox + oy * oy + oz * oz), EPSN);
            float r = 1.0f / l;
            out_final[pt * 3 + 0] = ox * r;
            out_final[pt * 3 + 1] = oy * r;
            out_final[pt * 3 + 2] = oz * r;
        } else {
            pout[pt] = make_float4(ox, oy, oz, 0.0f);
        }
    }
}

// ---------------------------------------------------------------------------
extern "C" void kernel_launch(void* const* d_in, const int* in_sizes, int n_in,
                              void* d_out, int out_size, void* d_ws, size_t ws_size,
                              hipStream_t stream)
{
    const float* x = (const float*)d_in[0];
    const float* v = (const float*)d_in[1];
    const int*   f = (const int*)d_in[2];
    float* out = (float*)d_out;

    const int N = in_sizes[1] / 3;   // 10242
    const int F = in_sizes[2] / 3;   // 20480

    char* ws = (char*)d_ws;
    float*  cx = (float*)ws;                       // F floats
    float*  cy = cx + F;
    float*  cz = cy + F;
    size_t off = (size_t)3 * F * sizeof(float);    // 245760, 16B aligned
    float4* v4 = (float4*)(ws + off);  off += (size_t)N * sizeof(float4);
    float4* p0 = (float4*)(ws + off);  off += (size_t)N * sizeof(float4);
    float4* p1 = (float4*)(ws + off);

    centers_kernel<<<(F + 255) / 256, 256, 0, stream>>>(f, v, cx, cy, cz, F);
    init_kernel<<<(N + 255) / 256, 256, 0, stream>>>(x, v, v4, p0, N);

    const int blocks = (N + 3) / 4;  // 4 points (waves) per block
    float4* pin = p0;
    float4* pout = p1;
    for (int k = 0; k < 6; ++k) {
        bool last = (k == 5);
        iter_kernel<<<blocks, 256, 0, stream>>>(
            pin, pout, cx, cy, cz, f, v4,
            last ? out : nullptr, N, F);
        float4* t = pin; pin = pout; pout = t;
    }
}

// Round 2
// 128.119 us; speedup vs baseline: 3.7769x; 3.7769x over previous
//
#include <hip/hip_runtime.h>
#include <hip/hip_bf16.h>
#include <math.h>

#define EPSN 1e-12f
#define MARGIN 0.02f   // prune threshold; ancestor bound is ~0.018 (see notes)

// ---------------------------------------------------------------------------
// Fine face centers (AoS float4): normalize(mean of 3 vertices)
// ---------------------------------------------------------------------------
__global__ __launch_bounds__(256)
void centers_kernel(const int* __restrict__ f,
                    const float* __restrict__ v,
                    float4* __restrict__ fine4,
                    int F)
{
    int i = blockIdx.x * 256 + threadIdx.x;
    if (i >= F) return;
    int a = f[i * 3 + 0], b = f[i * 3 + 1], c = f[i * 3 + 2];
    float mx = (v[a * 3 + 0] + v[b * 3 + 0] + v[c * 3 + 0]) * (1.0f / 3.0f);
    float my = (v[a * 3 + 1] + v[b * 3 + 1] + v[c * 3 + 1]) * (1.0f / 3.0f);
    float mz = (v[a * 3 + 2] + v[b * 3 + 2] + v[c * 3 + 2]) * (1.0f / 3.0f);
    float r = 1.0f / fmaxf(sqrtf(mx * mx + my * my + mz * mz), EPSN);
    fine4[i] = make_float4(mx * r, my * r, mz * r, 0.0f);
}

// ---------------------------------------------------------------------------
// Coarse (level-2) centroids: normalize(sum of the 64 descendant fine centers).
// Children of coarse c are fine faces 64c..64c+63 (faces subdivide 4-way in
// order, 3 levels from L2 to L5).  One wave per coarse face.
// ---------------------------------------------------------------------------
__global__ __launch_bounds__(256)
void coarse_kernel(const float4* __restrict__ fine4,
                   float4* __restrict__ coarse4,
                   int C)
{
    int t = blockIdx.x * 256 + threadIdx.x;
    int c = t >> 6, lane = t & 63;
    if (c >= C) return;
    float4 fc = fine4[(c << 6) + lane];
    float sx = fc.x, sy = fc.y, sz = fc.z;
    for (int off = 32; off >= 1; off >>= 1) {
        sx += __shfl_xor(sx, off);
        sy += __shfl_xor(sy, off);
        sz += __shfl_xor(sz, off);
    }
    if (lane == 0) {
        float r = 1.0f / fmaxf(sqrtf(sx * sx + sy * sy + sz * sz), EPSN);
        coarse4[c] = make_float4(sx * r, sy * r, sz * r, 0.0f);
    }
}

// ---------------------------------------------------------------------------
// Init: rotation frame -> axis/angle -> Rodrigues rotate v.  Packs v as float4.
// ---------------------------------------------------------------------------
__global__ __launch_bounds__(256)
void init_kernel(const float* __restrict__ x,
                 const float* __restrict__ v,
                 float4* __restrict__ v4,
                 float4* __restrict__ p0,
                 int N)
{
    int n = blockIdx.x * 256 + threadIdx.x;
    if (n >= N) return;

    float ax = x[n * 6 + 0], ay = x[n * 6 + 1], az = x[n * 6 + 2];
    float bx = x[n * 6 + 3], by = x[n * 6 + 4], bz = x[n * 6 + 5];

    float l = fmaxf(sqrtf(ax * ax + ay * ay + az * az), EPSN);
    float rxx = ax / l, rxy = ay / l, rxz = az / l;
    float czx = rxy * bz - rxz * by;
    float czy = rxz * bx - rxx * bz;
    float czz = rxx * by - rxy * bx;
    l = fmaxf(sqrtf(czx * czx + czy * czy + czz * czz), EPSN);
    float rzx = czx / l, rzy = czy / l, rzz = czz / l;
    float cyx = rzy * rxz - rzz * rxy;
    float cyy = rzz * rxx - rzx * rxz;
    float cyz = rzx * rxy - rzy * rxx;
    l = fmaxf(sqrtf(cyx * cyx + cyy * cyy + cyz * cyz), EPSN);
    float ryx = cyx / l, ryy = cyy / l, ryz = cyz / l;

    float axx = ryz - rzy;
    float axy = rzx - rxz;
    float axz = rxy - ryx;
    float trace = (rxx + ryy + rzz - 1.0f) * 0.5f;
    trace = fminf(fmaxf(trace, -1.0f + 1e-7f), 1.0f - 1e-7f);
    float angle = -acosf(trace) * (1.0f / 64.0f);   // / 2^K, K=6
    l = fmaxf(sqrtf(axx * axx + axy * axy + axz * axz), EPSN);
    axx /= l; axy /= l; axz /= l;

    float vx = v[n * 3 + 0], vy = v[n * 3 + 1], vz = v[n * 3 + 2];
    float d = axx * vx + axy * vy + axz * vz;
    float crx = axy * vz - axz * vy;
    float cry = axz * vx - axx * vz;
    float crz = axx * vy - axy * vx;
    float s, c;
    sincosf(angle, &s, &c);
    float omc = 1.0f - c;
    p0[n] = make_float4(vx * c + crx * s + axx * (d * omc),
                        vy * c + cry * s + axy * (d * omc),
                        vz * c + crz * s + axz * (d * omc), 0.0f);
    v4[n] = make_float4(vx, vy, vz, 0.0f);
}

// ---------------------------------------------------------------------------
// One deformation iteration.  One wave per point, no LDS, no __syncthreads.
// Two-level argmax: 320 coarse centroids (5/lane, registers) -> threshold
// prune -> expand each surviving coarse's 64 children (one per lane,
// coalesced float4 load from L2).
// ---------------------------------------------------------------------------
__global__ __launch_bounds__(256)
void iter_kernel(const float4* __restrict__ pin,
                 float4* __restrict__ pout,
                 const float4* __restrict__ fine4,
                 const float4* __restrict__ coarse4,
                 const int* __restrict__ f,
                 const float4* __restrict__ v4,
                 float* __restrict__ out_final,   // non-null on last iteration
                 int N)
{
    const int tid  = threadIdx.x;
    const int wave = tid >> 6;
    const int lane = tid & 63;
    const int pt   = blockIdx.x * 4 + wave;
    if (pt >= N) return;      // whole wave exits together; no block barriers

    float4 p = pin[pt];
    float rl = 1.0f / fmaxf(sqrtf(p.x * p.x + p.y * p.y + p.z * p.z), EPSN);
    float pnx = p.x * rl, pny = p.y * rl, pnz = p.z * rl;

    // ---- phase 1: coarse scores, 5 named slots per lane (no reg arrays) ----
    float4 c0 = coarse4[lane];
    float4 c1 = coarse4[lane + 64];
    float4 c2 = coarse4[lane + 128];
    float4 c3 = coarse4[lane + 192];
    float4 c4 = coarse4[lane + 256];
    float s0 = pnx * c0.x + pny * c0.y + pnz * c0.z;
    float s1 = pnx * c1.x + pny * c1.y + pnz * c1.z;
    float s2 = pnx * c2.x + pny * c2.y + pnz * c2.z;
    float s3 = pnx * c3.x + pny * c3.y + pnz * c3.z;
    float s4 = pnx * c4.x + pny * c4.y + pnz * c4.z;

    float bs = fmaxf(fmaxf(fmaxf(s0, s1), fmaxf(s2, s3)), s4);
    for (int off = 32; off >= 1; off >>= 1)
        bs = fmaxf(bs, __shfl_xor(bs, off));
    const float thr = bs - MARGIN;

    // ---- phase 2: expand surviving coarse faces' children -----------------
    float best = -1e30f;
    int bidx = 0;
    unsigned long long m;
    #define EXPAND(CC)                                                        \
        {                                                                     \
            int cand = ((CC) << 6) + lane;                                    \
            float4 fc = fine4[cand];                                          \
            float sc = pnx * fc.x + pny * fc.y + pnz * fc.z;                  \
            if (sc > best) { best = sc; bidx = cand; }                        \
        }
    m = __ballot(s0 >= thr);
    while (m) { int src = __ffsll(m) - 1; m &= m - 1; EXPAND(src); }
    m = __ballot(s1 >= thr);
    while (m) { int src = __ffsll(m) - 1; m &= m - 1; EXPAND(src + 64); }
    m = __ballot(s2 >= thr);
    while (m) { int src = __ffsll(m) - 1; m &= m - 1; EXPAND(src + 128); }
    m = __ballot(s3 >= thr);
    while (m) { int src = __ffsll(m) - 1; m &= m - 1; EXPAND(src + 192); }
    m = __ballot(s4 >= thr);
    while (m) { int src = __ffsll(m) - 1; m &= m - 1; EXPAND(src + 256); }
    #undef EXPAND

    // wave argmax, first-occurrence (lowest index) tie-break like np.argmax
    for (int off = 32; off >= 1; off >>= 1) {
        float sx = __shfl_xor(best, off);
        int   ix = __shfl_xor(bidx, off);
        if (sx > best || (sx == best && ix < bidx)) { best = sx; bidx = ix; }
    }

    if (lane == 0) {
        int i0 = f[bidx * 3 + 0];
        int i1 = f[bidx * 3 + 1];
        int i2 = f[bidx * 3 + 2];
        float4 A = v4[i0];
        float4 B = v4[i1];
        float4 C = v4[i2];

        // Cramer; det cancels in normalized barycentrics
        float bcx = B.y * C.z - B.z * C.y;
        float bcy = B.z * C.x - B.x * C.z;
        float bcz = B.x * C.y - B.y * C.x;
        float D0 = pnx * bcx + pny * bcy + pnz * bcz;
        float pcx = pny * C.z - pnz * C.y;
        float pcy = pnz * C.x - pnx * C.z;
        float pcz = pnx * C.y - pny * C.x;
        float D1 = A.x * pcx + A.y * pcy + A.z * pcz;
        float bpx = B.y * pnz - B.z * pny;
        float bpy = B.z * pnx - B.x * pnz;
        float bpz = B.x * pny - B.y * pnx;
        float D2 = A.x * bpx + A.y * bpy + A.z * bpz;

        float inv = 1.0f / (D0 + D1 + D2);
        float w0 = D0 * inv, w1 = D1 * inv, w2 = D2 * inv;

        float4 q0 = pin[i0];
        float4 q1 = pin[i1];
        float4 q2 = pin[i2];
        float r0 = 1.0f / fmaxf(sqrtf(q0.x * q0.x + q0.y * q0.y + q0.z * q0.z), EPSN);
        float r1 = 1.0f / fmaxf(sqrtf(q1.x * q1.x + q1.y * q1.y + q1.z * q1.z), EPSN);
        float r2 = 1.0f / fmaxf(sqrtf(q2.x * q2.x + q2.y * q2.y + q2.z * q2.z), EPSN);

        float ox = w0 * q0.x * r0 + w1 * q1.x * r1 + w2 * q2.x * r2;
        float oy = w0 * q0.y * r0 + w1 * q1.y * r1 + w2 * q2.y * r2;
        float oz = w0 * q0.z * r0 + w1 * q1.z * r1 + w2 * q2.z * r2;

        if (out_final) {
            float r = 1.0f / fmaxf(sqrtf(ox * ox + oy * oy + oz * oz), EPSN);
            out_final[pt * 3 + 0] = ox * r;
            out_final[pt * 3 + 1] = oy * r;
            out_final[pt * 3 + 2] = oz * r;
        } else {
            pout[pt] = make_float4(ox, oy, oz, 0.0f);
        }
    }
}

// ---------------------------------------------------------------------------
extern "C" void kernel_launch(void* const* d_in, const int* in_sizes, int n_in,
                              void* d_out, int out_size, void* d_ws, size_t ws_size,
                              hipStream_t stream)
{
    const float* x = (const float*)d_in[0];
    const float* v = (const float*)d_in[1];
    const int*   f = (const int*)d_in[2];
    float* out = (float*)d_out;

    const int N = in_sizes[1] / 3;   // 10242
    const int F = in_sizes[2] / 3;   // 20480
    const int C = F >> 6;            // 320 level-2 coarse faces

    char* ws = (char*)d_ws;
    size_t off = 0;
    float4* fine4   = (float4*)(ws + off); off += (size_t)F * sizeof(float4);
    float4* coarse4 = (float4*)(ws + off); off += (size_t)C * sizeof(float4);
    float4* v4      = (float4*)(ws + off); off += (size_t)N * sizeof(float4);
    float4* p0      = (float4*)(ws + off); off += (size_t)N * sizeof(float4);
    float4* p1      = (float4*)(ws + off);

    centers_kernel<<<(F + 255) / 256, 256, 0, stream>>>(f, v, fine4, F);
    coarse_kernel<<<(C * 64 + 255) / 256, 256, 0, stream>>>(fine4, coarse4, C);
    init_kernel<<<(N + 255) / 256, 256, 0, stream>>>(x, v, v4, p0, N);

    const int blocks = (N + 3) / 4;  // 1 wave per point, 4 waves/block
    float4* pin = p0;
    float4* pout = p1;
    for (int k = 0; k < 6; ++k) {
        bool last = (k == 5);
        iter_kernel<<<blocks, 256, 0, stream>>>(
            pin, pout, fine4, coarse4, f, v4, last ? out : nullptr, N);
        float4* t = pin; pin = pout; pout = t;
    }
}